// Round 10
// baseline (74.678 us; speedup 1.0000x reference)
//
#include <hip/hip_runtime.h>
#include <hip/hip_bf16.h>

// Resonance synth: out(b,e,n) = sum_f env_f(n) * sin(2*pi*freq_f*(n+1))
//   freq_f = (MIN + SCALE*f0_be)*(f+1), aliased (>=1.0) harmonics contribute 0
//   env_f(n) = linear frame->sample interp of res^(t+1), 256 samples/frame.
//
// Round 10: clean occupancy retest. R9's scalarized 4-chain body hand-counts
// ~56-60 VGPR (E0..31 + 8 chain + 4 acc + 4 k2 + misc; R0..31 in SGPRs) --
// fits the 64-VGPR cap of __launch_bounds__(256,8) WITHOUT the array-spill
// confound that sank R7. CHUNKS=32 -> 2048 blocks = 8 blocks/CU = 8 waves/
// SIMD (2x R6 TLP). KIT=4 = one 4-sample group per thread.

#define NSAMP 32768
#define NFRM  128
#define NF    32
#define NPAIR 64
#define CHUNKS 32
#define CHUNK (NSAMP / CHUNKS)   // 1024 samples per block
#define KIT   (CHUNK / 256)      // 4 samples per thread = 1 group of 4

#define FOR_EACH_32(M) \
  M(0)  M(1)  M(2)  M(3)  M(4)  M(5)  M(6)  M(7) \
  M(8)  M(9)  M(10) M(11) M(12) M(13) M(14) M(15) \
  M(16) M(17) M(18) M(19) M(20) M(21) M(22) M(23) \
  M(24) M(25) M(26) M(27) M(28) M(29) M(30) M(31)

__device__ __forceinline__ float ldin(const void* p, int i, bool isbf) {
    if (isbf) {
        unsigned int w = ((unsigned int)((const unsigned short*)p)[i]) << 16;
        float f; __builtin_memcpy(&f, &w, 4); return f;
    }
    return ((const float*)p)[i];
}

// force a block-uniform float into an SGPR
__device__ __forceinline__ float rfl(float x) {
    int i; __builtin_memcpy(&i, &x, 4);
    i = __builtin_amdgcn_readfirstlane(i);
    float f; __builtin_memcpy(&f, &i, 4); return f;
}

extern "C" __global__ __launch_bounds__(256, 8)
void reson_kernel(const void* __restrict__ f0p,
                  const void* __restrict__ resp,
                  const void* __restrict__ facp,
                  void* __restrict__ outp)
{
    // dtype sniff: factors[0]==1.0f -> f32 word 0x3F800000; bf16 packs 0x40003F80
    const bool isbf = (((const unsigned int*)facp)[0] != 0x3F800000u);

    const int pair = blockIdx.x;             // 0..63
    const int y    = blockIdx.y;             // 0..31
    const int tid  = threadIdx.x;            // 0..255
    const int n0   = y * CHUNK + tid;

    const float MINF = (float)(40.0 / 11025.0);
    const float FSC  = (float)(3960.0 / 11025.0);

    __shared__ float sR[NF];
    __shared__ float sP[NF];                 // r^(4y), alias-masked to 0

    const float f0v = rfl(ldin(f0p, pair, isbf));
    const float sf0 = MINF + FSC * f0v;      // < 0.37
    const unsigned int Q1 = (unsigned int)((double)sf0 * 4294967296.0 + 0.5);
    const unsigned int Qs = Q1 << 8;         // phase step per sample-row (256)

    if (tid < NF) {
        const float r   = ldin(resp, pair * NF + tid, isbf);
        const float fac = ldin(facp, tid, isbf);
        float P = exp2f(log2f(r) * (float)(4 * y));   // r^(4y); y==0 -> 1
        if (sf0 * fac >= 1.0f) P = 0.0f;              // aliased harmonic
        sR[tid] = r;
        sP[tid] = P;
    }
    __syncthreads();

    const float c0raw = (n0 + 0.5f) * (1.0f / 256.0f) - 0.5f;
    // frame-endpoint exponent i0c+1 is 4y (lo half, y>0) or 4y+1 (hi half / y==0)
    const bool useR1 = (tid >= 128) || (y == 0);

    // ---- named scalar state: E0..E31 (VGPR), R0..R31 (SGPR via rfl) ----
#define DECL_ER(f) float E##f, R##f;
    FOR_EACH_32(DECL_ER)
#undef DECL_ER
#define INIT_ER(f) { R##f = rfl(sR[f]); const float P = sP[f]; \
                     E##f = useR1 ? P * R##f : P; }
    FOR_EACH_32(INIT_ER)
#undef INIT_ER

    const int obase = pair * NSAMP + n0;
    unsigned int qn = Q1 * (unsigned int)(n0 + 1);   // phase of first sample

    if (y != 0 && y != CHUNKS - 1) {
        // ---- interior: fold w0 once, then env advances by *R per sample ----
        const float w0 = c0raw - floorf(c0raw);      // no clamps possible
#define FOLD(f) { const float M = E##f; E##f = fmaf(w0, fmaf(M, R##f, -M), M); }
        FOR_EACH_32(FOLD)
#undef FOLD
        // single group: 4 samples, 4 independent Chebyshev chains
        const unsigned int q0 = qn;
        const unsigned int q1 = qn + Qs;
        const unsigned int q2 = q1 + Qs;
        const unsigned int q3 = q2 + Qs;
        const float s0v = __builtin_amdgcn_sinf((float)q0 * 0x1p-32f);
        const float c0v = __builtin_amdgcn_cosf((float)q0 * 0x1p-32f);
        const float s1v = __builtin_amdgcn_sinf((float)q1 * 0x1p-32f);
        const float c1v = __builtin_amdgcn_cosf((float)q1 * 0x1p-32f);
        const float s2v = __builtin_amdgcn_sinf((float)q2 * 0x1p-32f);
        const float c2v = __builtin_amdgcn_cosf((float)q2 * 0x1p-32f);
        const float s3v = __builtin_amdgcn_sinf((float)q3 * 0x1p-32f);
        const float c3v = __builtin_amdgcn_cosf((float)q3 * 0x1p-32f);
        const float k20 = c0v + c0v, k21 = c1v + c1v;
        const float k22 = c2v + c2v, k23 = c3v + c3v;
        float sp0 = 0.f, sc0 = s0v, sp1 = 0.f, sc1 = s1v;
        float sp2 = 0.f, sc2 = s2v, sp3 = 0.f, sc3 = s3v;
        float a0 = 0.f, a1 = 0.f, a2 = 0.f, a3 = 0.f;
#define STEP(f) { \
        const float e1 = E##f * R##f; \
        const float e2 = e1 * R##f; \
        const float e3 = e2 * R##f; \
        a0 = fmaf(E##f, sc0, a0); \
        a1 = fmaf(e1,   sc1, a1); \
        a2 = fmaf(e2,   sc2, a2); \
        a3 = fmaf(e3,   sc3, a3); \
        E##f = e3 * R##f; \
        float sn; \
        sn = fmaf(k20, sc0, -sp0); sp0 = sc0; sc0 = sn; \
        sn = fmaf(k21, sc1, -sp1); sp1 = sc1; sc1 = sn; \
        sn = fmaf(k22, sc2, -sp2); sp2 = sc2; sc2 = sn; \
        sn = fmaf(k23, sc3, -sp3); sp3 = sc3; sc3 = sn; }
        FOR_EACH_32(STEP)
#undef STEP
        if (isbf) {
            __hip_bfloat16* op = (__hip_bfloat16*)outp;
            op[obase]       = __float2bfloat16(a0);
            op[obase + 256] = __float2bfloat16(a1);
            op[obase + 512] = __float2bfloat16(a2);
            op[obase + 768] = __float2bfloat16(a3);
        } else {
            float* op = (float*)outp;
            op[obase] = a0; op[obase + 256] = a1;
            op[obase + 512] = a2; op[obase + 768] = a3;
        }
    } else {
        // ---- edge blocks (y==0 clamp-low, y==31 clamp-high): general interp ----
        const float c0c = fminf(fmaxf(c0raw, 0.0f), 127.0f);
        const float w0 = c0c - floorf(c0c);
        const float c1e = c0raw + 1.0f;
        const float w1 = c1e - floorf(c1e);
        const bool clampLow = (y == 0) && (c0raw < 0.0f);
        #pragma unroll 1
        for (int k = 0; k < KIT; ++k) {
            const float t  = (float)qn * 0x1p-32f;
            const float sv = __builtin_amdgcn_sinf(t);
            const float cv = __builtin_amdgcn_cosf(t);
            const float k2 = cv + cv;
            float sp = 0.0f, sc = sv;
            const float wk = (k == 0)
                ? w0 : ((c0raw + (float)k > 127.0f) ? 0.0f : w1);
            const bool adv = !((k == 0) && clampLow); // clamped lanes hold frame 0
            float a0 = 0.0f, a1 = 0.0f;
#define ESTEP(f) { \
            const float M   = E##f; \
            const float An  = M * R##f; \
            const float env = fmaf(wk, An - M, M); \
            if ((f) & 1) a1 = fmaf(env, sc, a1); \
            else         a0 = fmaf(env, sc, a0); \
            E##f = adv ? An : M; \
            const float sn = fmaf(k2, sc, -sp); sp = sc; sc = sn; }
            FOR_EACH_32(ESTEP)
#undef ESTEP
            const float acc = a0 + a1;
            const int o = obase + (k << 8);
            if (isbf) ((__hip_bfloat16*)outp)[o] = __float2bfloat16(acc);
            else      ((float*)outp)[o] = acc;
            qn += Qs;
        }
    }
}

extern "C" void kernel_launch(void* const* d_in, const int* in_sizes, int n_in,
                              void* d_out, int out_size, void* d_ws, size_t ws_size,
                              hipStream_t stream) {
    (void)in_sizes; (void)n_in; (void)out_size; (void)d_ws; (void)ws_size;
    dim3 grid(NPAIR, CHUNKS);   // 64 x 32 = 2048 blocks = 8 blocks/CU
    dim3 block(256);
    reson_kernel<<<grid, block, 0, stream>>>(d_in[0], d_in[1], d_in[2], d_out);
}

// Round 11
// 66.309 us; speedup vs baseline: 1.1262x; 1.1262x over previous
//
#include <hip/hip_runtime.h>
#include <hip/hip_bf16.h>

// Resonance synth: out(b,e,n) = sum_f env_f(n) * sin(2*pi*freq_f*(n+1))
//   freq_f = (MIN + SCALE*f0_be)*(f+1), aliased (>=1.0) harmonics contribute 0
//   env_f(n) = linear frame->sample interp of res^(t+1), 256 samples/frame.
//
// FINAL (= round 6, best measured: 66.2 us):
//   - Chebyshev harmonic recurrence: all 32 harmonics share base angle
//     theta = 2*pi*frac(sf0*nn) (u32 fixed-point phase, exact mod-1);
//     sin(f*theta) via s_{f+1} = 2cos(theta)*s_f - s_{f-1} -> 1 sin + 1 cos
//     per sample instead of 32 sins. Rotation recurrence => bounded error.
//   - env: E[f] *= R[f] per k-step (interior blocks; w is per-thread const
//     and frame advances exactly 1/k-step). R[] block-uniform -> SGPRs.
//   - grid 64x16 = 1024 blocks = 4 blocks/CU tail-free, (256,4): best
//     measured config (R7/R10 showed more waves doesn't help; R2/R7 showed
//     tighter VGPR caps spill).
// Session conclusion: bench = ~42us harness ws-poison fill (80%+ HBM peak,
// memory-roofline-bound) + ~20us fixed replay overhead + ~4-6us kernel.
// Kernel is within ~2x of its pure VALU issue floor; remaining controllable
// time is below session noise.

#define NSAMP 32768
#define NFRM  128
#define NF    32
#define NPAIR 64
#define CHUNKS 16
#define CHUNK (NSAMP / CHUNKS)   // 2048 samples per block
#define KIT   (CHUNK / 256)      // 8 samples per thread, 8 frames per block

__device__ __forceinline__ float ldin(const void* p, int i, bool isbf) {
    if (isbf) {
        unsigned int w = ((unsigned int)((const unsigned short*)p)[i]) << 16;
        float f; __builtin_memcpy(&f, &w, 4); return f;
    }
    return ((const float*)p)[i];
}

// force a block-uniform float into an SGPR
__device__ __forceinline__ float rfl(float x) {
    int i; __builtin_memcpy(&i, &x, 4);
    i = __builtin_amdgcn_readfirstlane(i);
    float f; __builtin_memcpy(&f, &i, 4); return f;
}

extern "C" __global__ __launch_bounds__(256, 4)
void reson_kernel(const void* __restrict__ f0p,
                  const void* __restrict__ resp,
                  const void* __restrict__ facp,
                  void* __restrict__ outp)
{
    // dtype sniff: factors[0]==1.0f -> f32 word 0x3F800000; bf16 packs 0x40003F80
    const bool isbf = (((const unsigned int*)facp)[0] != 0x3F800000u);

    const int pair = blockIdx.x;             // 0..63
    const int y    = blockIdx.y;             // 0..15
    const int tid  = threadIdx.x;            // 0..255
    const int n0   = y * CHUNK + tid;

    const float MINF = (float)(40.0 / 11025.0);
    const float FSC  = (float)(3960.0 / 11025.0);

    __shared__ float sR[NF];
    __shared__ float sP[NF];                 // r^(8y), alias-masked to 0

    const float f0v = rfl(ldin(f0p, pair, isbf));
    const float sf0 = MINF + FSC * f0v;      // < 0.37
    const unsigned int Q1 = (unsigned int)((double)sf0 * 4294967296.0 + 0.5);

    if (tid < NF) {
        const float r   = ldin(resp, pair * NF + tid, isbf);
        const float fac = ldin(facp, tid, isbf);
        float P = exp2f(log2f(r) * (float)(8 * y));   // r^(8y); y==0 -> 1
        if (sf0 * fac >= 1.0f) P = 0.0f;              // aliased harmonic
        sR[tid] = r;
        sP[tid] = P;
    }
    __syncthreads();

    const float c0raw = (n0 + 0.5f) * (1.0f / 256.0f) - 0.5f;
    // frame-endpoint exponent i0c+1 is 8y (lo half, y>0) or 8y+1 (hi half / y==0)
    const bool useR1 = (tid >= 128) || (y == 0);

    float E[NF];     // per-thread env state
    float Rg[NF];    // block-uniform -> SGPRs
    #pragma unroll
    for (int f4 = 0; f4 < NF; f4 += 4) {
        const float4 p4 = *(const float4*)&sP[f4];   // ds_read_b128, broadcast
        const float4 r4 = *(const float4*)&sR[f4];
        Rg[f4+0] = rfl(r4.x); Rg[f4+1] = rfl(r4.y);
        Rg[f4+2] = rfl(r4.z); Rg[f4+3] = rfl(r4.w);
        E[f4+0] = useR1 ? p4.x * Rg[f4+0] : p4.x;
        E[f4+1] = useR1 ? p4.y * Rg[f4+1] : p4.y;
        E[f4+2] = useR1 ? p4.z * Rg[f4+2] : p4.z;
        E[f4+3] = useR1 ? p4.w * Rg[f4+3] : p4.w;
    }

    const int obase = pair * NSAMP + n0;

    if (y != 0 && y != CHUNKS - 1) {
        // ---- interior: fold w0 once, then env_k = env_0 * r^k ----
        const float w0 = c0raw - floorf(c0raw);      // no clamps possible
        #pragma unroll
        for (int f = 0; f < NF; ++f) {
            const float M = E[f];
            E[f] = fmaf(w0, fmaf(M, Rg[f], -M), M);  // M + w0*(M*r - M)
        }
        #pragma unroll 1
        for (int k = 0; k < KIT; ++k) {
            const unsigned int nn = (unsigned int)(n0 + (k << 8) + 1);
            const unsigned int qn = Q1 * nn;          // base phase, u32 turns
            const float t  = (float)qn * 0x1p-32f;    // [0,1) revolutions
            const float s1 = __builtin_amdgcn_sinf(t);
            const float c1 = __builtin_amdgcn_cosf(t);
            const float k2 = c1 + c1;                 // 2*cos(theta)
            float sp = 0.0f, sc = s1;                 // sin(0), sin(theta)
            float a0 = 0.0f, a1 = 0.0f;
            #pragma unroll
            for (int f = 0; f < NF; ++f) {
                if (f & 1) a1 = fmaf(E[f], sc, a1);
                else       a0 = fmaf(E[f], sc, a0);
                E[f] *= Rg[f];
                const float sn = fmaf(k2, sc, -sp);   // sin((f+2)*theta)
                sp = sc; sc = sn;
            }
            const float acc = a0 + a1;
            const int o = obase + (k << 8);
            if (isbf) ((__hip_bfloat16*)outp)[o] = __float2bfloat16(acc);
            else      ((float*)outp)[o] = acc;
        }
    } else {
        // ---- edge blocks (y==0 clamp-low, y==15 clamp-high): general interp ----
        const float c0 = fminf(fmaxf(c0raw, 0.0f), 127.0f);
        const float w0 = c0 - floorf(c0);
        const float c1e = c0raw + 1.0f;
        const float w1 = c1e - floorf(c1e);
        const bool clampLow = (y == 0) && (c0raw < 0.0f);
        #pragma unroll 1
        for (int k = 0; k < KIT; ++k) {
            const unsigned int nn = (unsigned int)(n0 + (k << 8) + 1);
            const unsigned int qn = Q1 * nn;
            const float t  = (float)qn * 0x1p-32f;
            const float s1 = __builtin_amdgcn_sinf(t);
            const float cc = __builtin_amdgcn_cosf(t);
            const float k2 = cc + cc;
            float sp = 0.0f, sc = s1;
            const float wk = (k == 0)
                ? w0 : ((c0raw + (float)k > 127.0f) ? 0.0f : w1);
            const bool adv = !((k == 0) && clampLow); // clamped lanes hold frame 0
            float a0 = 0.0f, a1 = 0.0f;
            #pragma unroll
            for (int f = 0; f < NF; ++f) {
                const float M   = E[f];
                const float An  = M * Rg[f];
                const float env = fmaf(wk, An - M, M);
                if (f & 1) a1 = fmaf(env, sc, a1);
                else       a0 = fmaf(env, sc, a0);
                E[f] = adv ? An : M;
                const float sn = fmaf(k2, sc, -sp);
                sp = sc; sc = sn;
            }
            const float acc = a0 + a1;
            const int o = obase + (k << 8);
            if (isbf) ((__hip_bfloat16*)outp)[o] = __float2bfloat16(acc);
            else      ((float*)outp)[o] = acc;
        }
    }
}

extern "C" void kernel_launch(void* const* d_in, const int* in_sizes, int n_in,
                              void* d_out, int out_size, void* d_ws, size_t ws_size,
                              hipStream_t stream) {
    (void)in_sizes; (void)n_in; (void)out_size; (void)d_ws; (void)ws_size;
    dim3 grid(NPAIR, CHUNKS);   // 64 x 16 = 1024 blocks = 4 blocks/CU, tail-free
    dim3 block(256);
    reson_kernel<<<grid, block, 0, stream>>>(d_in[0], d_in[1], d_in[2], d_out);
}